// Round 13
// baseline (116.639 us; speedup 1.0000x reference)
//
#include <hip/hip_runtime.h>

// Fused upfirdn2d: up2(FIR12,H) -> up2(FIR12,W) -> +bias -> lrelu*sqrt2
//                  -> down2(FIR12,H) -> down2(FIR12,W)
// x: (32,128,64,64) f32.
// R13: DUAL-QUARTER SOFTWARE-PIPELINED BLOCK (NT=512, 8192 blocks).
//   R5-R12 data: separate-phase structure plateaus 73-75us with VALU~60%,
//   LDS~60%, occupancy~65% -- nothing saturated. Theory: identical block
//   durations keep resident blocks in lockstep generations; at each
//   generation boundary ALL waves sit in P1's global-load shadow.
//   Fix: each block runs quarters A then B; B's x loads are issued into
//   REGISTERS before P4.A (hidden under P4.A + barrier drain), z.B computed
//   from staged regs. Halves boundaries, removes B's load stall.
//   Phase bodies identical to R10 (proven): bank-clean lane maps, groups
//   padded to multiples of 8, yw aliases z region, 39KB LDS -> 4 blk/CU.
//
// Index math:
//   z[i][c]  = sum_{j == i (mod 2)} (2*fu[j]) * x[(i-j)/2][c]
//   y[i][w]  = sum_{j == w (mod 2)} (2*fu[j]) * z[i][(w-j)/2]; lrelu(y+b)*g
//   yw[i][p] = sum_{j} fd[j] * y[i][2p+11-j]          (down-W; commutes w/ down-H)
//   out[o][p]= sum_{j} fd[j] * yw[2o+11-j][p]         (down-H)

#define NT 512
#define GAIN 1.41421356237309504880f
#define C1 (0.6f * GAIN)
#define C2 (0.4f * GAIN)

#define ZROWS 42              // quarter: out rows [o0,o0+16) -> z/y rows [2o0,2o0+42)
#define ZSTRIDE 84            // 336B = 80B mod 128 -> full rotation, row-walk
#define ZPAD 8                // local col p <-> real z col p-8 ; pads zeroed
#define YSTRIDE 148           // 592B = 80B mod 128 -> full rotation, row-walk
#define YWSTRIDE 68           // 272B = 16B mod 128 -> full rotation, row-walk

#define ZB_OFF 0
#define YB_OFF (ZROWS * ZSTRIDE)              // 3528
#define YW_OFF 0                              // yw[42][68]=2856 aliases zb
#define LDS_FLOATS (YB_OFF + ZROWS * YSTRIDE) // 9744 floats = 38976 B -> 4 blk/CU

// wave-uniform float -> SGPR
__device__ __forceinline__ float sload(float v) {
    return __uint_as_float(__builtin_amdgcn_readfirstlane(__float_as_uint(v)));
}

__device__ __forceinline__ void load6(float4* xv, const float* __restrict__ xg,
                                      int M, int c4) {
    if (M >= 5 && M <= 63) {              // interior: no bounds checks
#pragma unroll
        for (int d = 0; d < 6; ++d)
            xv[d] = *reinterpret_cast<const float4*>(xg + (M - 5 + d) * 64 + c4);
    } else {
#pragma unroll
        for (int d = 0; d < 6; ++d) {
            const int r = M - 5 + d;
            xv[d] = (r >= 0 && r <= 63)
                  ? *reinterpret_cast<const float4*>(xg + r * 64 + c4)
                  : make_float4(0.f, 0.f, 0.f, 0.f);
        }
    }
}

// up-H: z rows 2m,2m+1 from xv[0..5]; weights fu[2(5-d)], fu[2(5-d)+1]
__device__ __forceinline__ void uph(const float4* xv, const float* fu,
                                    float* a0, float* a1) {
#pragma unroll
    for (int k = 0; k < 4; ++k) { a0[k] = 0.f; a1[k] = 0.f; }
#pragma unroll
    for (int d = 0; d < 6; ++d) {
        const float w0 = fu[2 * (5 - d)], w1 = fu[2 * (5 - d) + 1];
        a0[0] += w0 * xv[d].x; a0[1] += w0 * xv[d].y; a0[2] += w0 * xv[d].z; a0[3] += w0 * xv[d].w;
        a1[0] += w1 * xv[d].x; a1[1] += w1 * xv[d].y; a1[2] += w1 * xv[d].z; a1[3] += w1 * xv[d].w;
    }
}

__device__ __forceinline__ void zwrite(float* zb, int m, int c4,
                                       const float* a0, const float* a1) {
    float* zr = zb + (2 * m) * ZSTRIDE + ZPAD + c4;
    *reinterpret_cast<float4*>(zr)           = make_float4(a0[0], a0[1], a0[2], a0[3]);
    *reinterpret_cast<float4*>(zr + ZSTRIDE) = make_float4(a1[0], a1[1], a1[2], a1[3]);
}

__device__ __forceinline__ void padzero(float* zb, int t) {
    // zero z pad cols [0,8) and [72,84): 5 float4 per row x 42 rows = 210 tasks
    for (int pt = t - 336; pt < 210; pt += 176) {
        const int rl = pt / 5;
        const int p = pt - rl * 5;
        const int col = (p < 2) ? (p << 2) : (72 + ((p - 2) << 2));
        *reinterpret_cast<float4*>(zb + rl * ZSTRIDE + col) = make_float4(0.f, 0.f, 0.f, 0.f);
    }
}

// P2: up-W + bias + lrelu -> y[42][148]; groups of 48, il fast-varying
__device__ __forceinline__ void p2(const float* zb, float* yb, int t,
                                   const float* fu, float bv) {
    if (t >= 432) return;
    const int cg = t / 48;                // 0..8
    const int il = t - cg * 48;
    if (il >= ZROWS) return;
    const int mbase = cg << 3;
    const float* zr = zb + il * ZSTRIDE + mbase;   // local col = real col + 8
    float zv[16];
#pragma unroll
    for (int q = 0; q < 4; ++q) {
        const float4 v = *reinterpret_cast<const float4*>(zr + (q << 2));
        zv[4 * q] = v.x; zv[4 * q + 1] = v.y; zv[4 * q + 2] = v.z; zv[4 * q + 3] = v.w;
    }
    float yv[16];
#pragma unroll
    for (int e = 0; e < 8; ++e) {         // m = mbase+e -> w = 2m, 2m+1
        float a0 = bv, a1 = bv;
#pragma unroll
        for (int tt = 0; tt < 6; ++tt) {
            const float zz = zv[8 + e - tt];
            a0 += fu[2 * tt]     * zz;
            a1 += fu[2 * tt + 1] * zz;
        }
        yv[2 * e]     = C1 * a0 + C2 * fabsf(a0);   // g*lrelu
        yv[2 * e + 1] = C1 * a1 + C2 * fabsf(a1);
    }
    float* yr = yb + il * YSTRIDE + (mbase << 1);
#pragma unroll
    for (int q = 0; q < 4; ++q)
        *reinterpret_cast<float4*>(yr + (q << 2)) =
            make_float4(yv[4 * q], yv[4 * q + 1], yv[4 * q + 2], yv[4 * q + 3]);
}

// P3: down-W on y -> yw[42][64] (in z region); groups of 48, il fast-varying
__device__ __forceinline__ void p3(const float* yb, float* yw, int t,
                                   const float* fd) {
    if (t >= 384) return;
    const int cg = t / 48;                // 0..7 ; outputs p = 8cg..8cg+7
    const int il = t - cg * 48;
    if (il >= ZROWS) return;
    const float* yr = yb + il * YSTRIDE + (cg << 4);   // y cols 16cg..16cg+27
    float w[28];
#pragma unroll
    for (int q = 0; q < 7; ++q) {
        const float4 v = *reinterpret_cast<const float4*>(yr + (q << 2));
        w[4 * q] = v.x; w[4 * q + 1] = v.y; w[4 * q + 2] = v.z; w[4 * q + 3] = v.w;
    }
    float rv[8];
#pragma unroll
    for (int e = 0; e < 8; ++e) {         // p = 8cg+e : y cols 2p..2p+11
        float a = 0.0f;
#pragma unroll
        for (int j = 0; j < 12; ++j) a += fd[j] * w[2 * e + 11 - j];
        rv[e] = a;
    }
    float* wr = yw + il * YWSTRIDE + (cg << 3);
    *reinterpret_cast<float4*>(wr)     = make_float4(rv[0], rv[1], rv[2], rv[3]);
    *reinterpret_cast<float4*>(wr + 4) = make_float4(rv[4], rv[5], rv[6], rv[7]);
}

// P4: down-H on yw -> global out rows [o0, o0+16)
__device__ __forceinline__ void p4(const float* yw, float* __restrict__ outg,
                                   int o0, int t, const float* fd) {
    if (t >= 64) return;
    const int eg = t >> 4;                // 0..3 ; out rows o0+4eg..o0+4eg+3
    const int col4 = (t & 15) << 2;       // 0..60
    const float* wr = yw + (eg << 3) * YWSTRIDE + col4;    // yw rows 8eg..8eg+17
    float acc[4][4] = {{0,0,0,0},{0,0,0,0},{0,0,0,0},{0,0,0,0}};
#pragma unroll
    for (int r = 0; r < 18; ++r) {
        const float4 v = *reinterpret_cast<const float4*>(wr + r * YWSTRIDE);
#pragma unroll
        for (int e = 0; e < 4; ++e) {
            if (r >= 2 * e && r <= 2 * e + 11) {           // compile-time per (r,e)
                const float ww = fd[11 - r + 2 * e];
                acc[e][0] += ww * v.x; acc[e][1] += ww * v.y;
                acc[e][2] += ww * v.z; acc[e][3] += ww * v.w;
            }
        }
    }
#pragma unroll
    for (int e = 0; e < 4; ++e)
        *reinterpret_cast<float4*>(outg + (o0 + (eg << 2) + e) * 64 + col4) =
            make_float4(acc[e][0], acc[e][1], acc[e][2], acc[e][3]);
}

__global__ __launch_bounds__(NT, 8) void fused_upfirdn_lrelu(
    const float* __restrict__ x,
    const float* __restrict__ bias,
    const float* __restrict__ upf,
    const float* __restrict__ dnf,
    float* __restrict__ out)
{
    extern __shared__ float lds[];
    float* zb = lds + ZB_OFF;
    float* yb = lds + YB_OFF;
    float* yw = lds + YW_OFF;     // aliases zb

    const int t = threadIdx.x;
    const int bid = blockIdx.x;
    const int s = bid >> 1;           // slice = n*128 + c
    const int h = bid & 1;
    const int o0A = h << 5;           // 0 or 32
    const int o0B = o0A + 16;         // 16 or 48
    const int c = s & 127;

    float fu[12], fd[12];
#pragma unroll
    for (int j = 0; j < 12; ++j) {
        fu[j] = sload(2.0f * upf[j]);
        fd[j] = sload(dnf[j]);
    }
    const float bv = sload(bias[c]);

    const float* xg = x + (size_t)s * 4096;
    float* outg = out + (size_t)s * 4096;

    const int p1_m  = t >> 4;             // 0..20 (valid for t<336)
    const int p1_c4 = (t & 15) << 2;

    float4 sx[6];

    // ================= quarter A =================
    if (t < 336) {
        load6(sx, xg, o0A + p1_m, p1_c4);
        float a0[4], a1[4];
        uph(sx, fu, a0, a1);
        zwrite(zb, p1_m, p1_c4, a0, a1);
    } else {
        padzero(zb, t);
    }
    __syncthreads();

    p2(zb, yb, t, fu, bv);
    __syncthreads();

    p3(yb, yw, t, fd);
    __syncthreads();

    // issue quarter-B x loads NOW; latency hides under P4.A + barrier drain
    if (t < 336) load6(sx, xg, o0B + p1_m, p1_c4);
    __builtin_amdgcn_sched_barrier(0);    // pin the load issue point

    p4(yw, outg, o0A, t, fd);
    __syncthreads();                      // drains vmcnt: B loads done here

    // ================= quarter B =================
    if (t < 336) {
        float a0[4], a1[4];
        uph(sx, fu, a0, a1);
        zwrite(zb, p1_m, p1_c4, a0, a1);  // overwrites yw.A (dead after P4.A)
    } else {
        padzero(zb, t);                   // re-zero pads (yw.A dirtied them)
    }
    __syncthreads();

    p2(zb, yb, t, fu, bv);
    __syncthreads();

    p3(yb, yw, t, fd);
    __syncthreads();

    p4(yw, outg, o0B, t, fd);
}

extern "C" void kernel_launch(void* const* d_in, const int* in_sizes, int n_in,
                              void* d_out, int out_size, void* d_ws, size_t ws_size,
                              hipStream_t stream) {
    const float* x    = (const float*)d_in[0];
    const float* bias = (const float*)d_in[1];
    const float* upf  = (const float*)d_in[2];
    const float* dnf  = (const float*)d_in[3];
    float* out = (float*)d_out;

    const int n_blocks = 32 * 128 * 2;   // two half-slices (A+B quarters) per (n,c)
    const size_t lds_bytes = (size_t)LDS_FLOATS * sizeof(float);
    hipLaunchKernelGGL(fused_upfirdn_lrelu, dim3(n_blocks), dim3(NT),
                       lds_bytes, stream, x, bias, upf, dnf, out);
}

// Round 14
// 79.658 us; speedup vs baseline: 1.4642x; 1.4642x over previous
//
#include <hip/hip_runtime.h>

// Fused upfirdn2d: up2(FIR12,H) -> up2(FIR12,W) -> +bias -> lrelu*sqrt2
//                  -> down2(FIR12,H) -> down2(FIR12,W)
// x: (32,128,64,64) f32.
// R14 = R10 quarter-slice separate-phase skeleton (FLOP-minimal, proven) with:
//   - y stored in LDS as BF16 pairs (v_cvt_pk_bf16_f32 pack; shift/and unpack):
//     P2 writes 4->2 b128, P3 reads 7->4 b128, y buffer halves. Accuracy
//     budget: absmax 0.0156 now vs 0.1056 threshold; bf16-y adds ~|y|*2^-9
//     through two ~1.3-gain filters -> expected ~0.03-0.07. If fail: revert.
//   - LDS 26.9KB, NT=384 (6 waves) -> 5 blocks/CU, 30/32 wave slots, 5
//     INDEPENDENT barrier groups (R10 had 4 lockstep 8-wave groups; pipe
//     accounting shows no pipe >65% busy -> serialization is the limiter).
//
// Index math:
//   z[i][c]  = sum_{j == i (mod 2)} (2*fu[j]) * x[(i-j)/2][c]
//   y[i][w]  = sum_{j == w (mod 2)} (2*fu[j]) * z[i][(w-j)/2]; lrelu(y+b)*g
//   yw[i][p] = sum_{j} fd[j] * y[i][2p+11-j]          (down-W; commutes w/ down-H)
//   out[o][p]= sum_{j} fd[j] * yw[2o+11-j][p]         (down-H)

#define NT 384
#define GAIN 1.41421356237309504880f
#define C1 (0.6f * GAIN)
#define C2 (0.4f * GAIN)

#define ZROWS 42              // quarter: out rows [o0,o0+16) -> z/y rows [2o0,2o0+42)
#define ZSTRIDE 84            // 336B = 80B mod 128 -> full rotation, row-walk
#define ZPAD 8                // local col p <-> real z col p-8 ; pads zeroed
#define YSTRIDE_U32 76        // bf16-pair row stride: 304B = 48B mod 128 -> full rotation
#define YWSTRIDE 68           // 272B = 16B mod 128 -> full rotation, row-walk

#define ZB_OFF 0
#define YB_OFF (ZROWS * ZSTRIDE)                   // 3528 (u32 units == float units)
#define YW_OFF 0                                   // yw[42][68] f32 aliases zb (dead after P2)
#define LDS_WORDS (YB_OFF + ZROWS * YSTRIDE_U32)   // 3528 + 3192 = 6720 words = 26880 B

// wave-uniform float -> SGPR
__device__ __forceinline__ float sload(float v) {
    return __uint_as_float(__builtin_amdgcn_readfirstlane(__float_as_uint(v)));
}

// pack two f32 -> one u32 of 2xbf16 (RTN), lo = a, hi = b
__device__ __forceinline__ unsigned int pk_bf16(float a, float b) {
    unsigned int r;
    asm("v_cvt_pk_bf16_f32 %0, %1, %2" : "=v"(r) : "v"(a), "v"(b));
    return r;
}

__global__ __launch_bounds__(NT, 8) void fused_upfirdn_lrelu(
    const float* __restrict__ x,
    const float* __restrict__ bias,
    const float* __restrict__ upf,
    const float* __restrict__ dnf,
    float* __restrict__ out)
{
    extern __shared__ float lds[];
    float* zb = lds + ZB_OFF;
    unsigned int* yb = reinterpret_cast<unsigned int*>(lds + YB_OFF);
    float* yw = lds + YW_OFF;     // aliases zb

    const int t = threadIdx.x;
    const int bid = blockIdx.x;
    const int s = bid >> 2;           // slice = n*128 + c
    const int o0 = (bid & 3) << 4;    // 0,16,32,48
    const int c = s & 127;

    // filters + bias in SGPRs (uniform); fu pre-scaled by UP=2
    float fu[12], fd[12];
#pragma unroll
    for (int j = 0; j < 12; ++j) {
        fu[j] = sload(2.0f * upf[j]);
        fd[j] = sload(dnf[j]);
    }
    const float bv = sload(bias[c]);

    const float* xg = x + (size_t)s * 4096;
    float* outg = out + (size_t)s * 4096;

    // ---- P1: up-H from GLOBAL x -> z local rows [0,42).  t<336: task=(m,c4),
    //      z rows 2m,2m+1 from x rows M-5..M (M=o0+m), interior unchecked.
    //      t>=336 (48 lanes): zero z pad cols [0,8) and [72,84), 210 tasks. ----
    if (t < 336) {
        const int m = t >> 4;                 // 0..20
        const int c4 = (t & 15) << 2;
        const int M = o0 + m;
        float4 xv[6];
        if (M >= 5 && M <= 63) {              // interior: no bounds checks
#pragma unroll
            for (int d = 0; d < 6; ++d)
                xv[d] = *reinterpret_cast<const float4*>(xg + (M - 5 + d) * 64 + c4);
        } else {
#pragma unroll
            for (int d = 0; d < 6; ++d) {
                const int r = M - 5 + d;
                xv[d] = (r >= 0 && r <= 63)
                      ? *reinterpret_cast<const float4*>(xg + r * 64 + c4)
                      : make_float4(0.f, 0.f, 0.f, 0.f);
            }
        }
        float a0[4] = {0,0,0,0}, a1[4] = {0,0,0,0};
#pragma unroll
        for (int d = 0; d < 6; ++d) {         // tt = 5-d
            const float w0 = fu[2 * (5 - d)], w1 = fu[2 * (5 - d) + 1];
            a0[0] += w0 * xv[d].x; a0[1] += w0 * xv[d].y; a0[2] += w0 * xv[d].z; a0[3] += w0 * xv[d].w;
            a1[0] += w1 * xv[d].x; a1[1] += w1 * xv[d].y; a1[2] += w1 * xv[d].z; a1[3] += w1 * xv[d].w;
        }
        float* zr = zb + (2 * m) * ZSTRIDE + ZPAD + c4;
        *reinterpret_cast<float4*>(zr)           = make_float4(a0[0], a0[1], a0[2], a0[3]);
        *reinterpret_cast<float4*>(zr + ZSTRIDE) = make_float4(a1[0], a1[1], a1[2], a1[3]);
    } else {
        // 5 float4 pad-writes per row x 42 rows = 210 tasks over 48 lanes
        for (int pt = t - 336; pt < 210; pt += 48) {
            const int rl = pt / 5;
            const int p = pt - rl * 5;
            const int col = (p < 2) ? (p << 2) : (72 + ((p - 2) << 2));
            *reinterpret_cast<float4*>(zb + rl * ZSTRIDE + col) = make_float4(0.f, 0.f, 0.f, 0.f);
        }
    }
    __syncthreads();

    // ---- P2: up-W + bias + lrelu -> y bf16 pairs [42][76 u32].
    //      432 tasks over 384 threads (t, and t+384 for t<48).
    //      Groups of 48 (mult of 8), il fast-varying -> bank-clean. ----
#pragma unroll
    for (int pass = 0; pass < 2; ++pass) {
        const int tt = t + pass * NT;
        if (pass == 1 && t >= 48) break;      // tasks 384..431 only
        const int cg = tt / 48;               // 0..8
        const int il = tt - cg * 48;
        if (il < ZROWS) {
            const int mbase = cg << 3;
            const float* zr = zb + il * ZSTRIDE + mbase;   // local col = real col + 8
            float zv[16];
#pragma unroll
            for (int q = 0; q < 4; ++q) {
                const float4 v = *reinterpret_cast<const float4*>(zr + (q << 2));
                zv[4 * q] = v.x; zv[4 * q + 1] = v.y; zv[4 * q + 2] = v.z; zv[4 * q + 3] = v.w;
            }
            unsigned int pk[8];
#pragma unroll
            for (int e = 0; e < 8; ++e) {     // m = mbase+e -> y cols 2m, 2m+1 (pair m)
                float a0 = bv, a1 = bv;
#pragma unroll
                for (int tq = 0; tq < 6; ++tq) {
                    const float zz = zv[8 + e - tq];
                    a0 += fu[2 * tq]     * zz;
                    a1 += fu[2 * tq + 1] * zz;
                }
                const float y0 = C1 * a0 + C2 * fabsf(a0);   // g*lrelu
                const float y1 = C1 * a1 + C2 * fabsf(a1);
                pk[e] = pk_bf16(y0, y1);      // lo = y_even, hi = y_odd
            }
            unsigned int* yr = yb + il * YSTRIDE_U32 + mbase;
            *reinterpret_cast<uint4*>(yr)     = make_uint4(pk[0], pk[1], pk[2], pk[3]);
            *reinterpret_cast<uint4*>(yr + 4) = make_uint4(pk[4], pk[5], pk[6], pk[7]);
        }
    }
    __syncthreads();

    // ---- P3: down-W on bf16 y -> yw[42][64] f32 (aliases zb).  384 tasks,
    //      groups of 48, il fast-varying.  4 b128 u32 reads, unpack 13 pairs. ----
    {
        const int cg = t / 48;                // 0..7 ; outputs p = 8cg..8cg+7
        const int il = t - cg * 48;
        if (il < ZROWS) {
            const unsigned int* yr = yb + il * YSTRIDE_U32 + (cg << 3);
            unsigned int u[16];
#pragma unroll
            for (int q = 0; q < 4; ++q) {
                const uint4 v = *reinterpret_cast<const uint4*>(yr + (q << 2));
                u[4 * q] = v.x; u[4 * q + 1] = v.y; u[4 * q + 2] = v.z; u[4 * q + 3] = v.w;
            }
            float w[26];                      // y cols 16cg .. 16cg+25
#pragma unroll
            for (int k = 0; k < 13; ++k) {
                w[2 * k]     = __uint_as_float(u[k] << 16);
                w[2 * k + 1] = __uint_as_float(u[k] & 0xffff0000u);
            }
            float rv[8];
#pragma unroll
            for (int e = 0; e < 8; ++e) {     // p = 8cg+e : y cols 2p..2p+11
                float a = 0.0f;
#pragma unroll
                for (int j = 0; j < 12; ++j) a += fd[j] * w[2 * e + 11 - j];
                rv[e] = a;
            }
            float* wr = yw + il * YWSTRIDE + (cg << 3);
            *reinterpret_cast<float4*>(wr)     = make_float4(rv[0], rv[1], rv[2], rv[3]);
            *reinterpret_cast<float4*>(wr + 4) = make_float4(rv[4], rv[5], rv[6], rv[7]);
        }
    }
    __syncthreads();

    // ---- P4: down-H on yw -> GLOBAL out.  t<64: task=(eg, col4): 4 out rows
    //      x 4 cols from 18 yw rows; col4 fast-varying -> bank-clean. ----
    if (t < 64) {
        const int eg = t >> 4;                // 0..3 ; out rows o0+4eg..o0+4eg+3
        const int col4 = (t & 15) << 2;       // 0..60
        const float* wr = yw + (eg << 3) * YWSTRIDE + col4;    // yw rows 8eg..8eg+17
        float acc[4][4] = {{0,0,0,0},{0,0,0,0},{0,0,0,0},{0,0,0,0}};
#pragma unroll
        for (int r = 0; r < 18; ++r) {
            const float4 v = *reinterpret_cast<const float4*>(wr + r * YWSTRIDE);
#pragma unroll
            for (int e = 0; e < 4; ++e) {
                if (r >= 2 * e && r <= 2 * e + 11) {           // compile-time per (r,e)
                    const float ww = fd[11 - r + 2 * e];
                    acc[e][0] += ww * v.x; acc[e][1] += ww * v.y;
                    acc[e][2] += ww * v.z; acc[e][3] += ww * v.w;
                }
            }
        }
#pragma unroll
        for (int e = 0; e < 4; ++e)
            *reinterpret_cast<float4*>(outg + (o0 + (eg << 2) + e) * 64 + col4) =
                make_float4(acc[e][0], acc[e][1], acc[e][2], acc[e][3]);
    }
}

extern "C" void kernel_launch(void* const* d_in, const int* in_sizes, int n_in,
                              void* d_out, int out_size, void* d_ws, size_t ws_size,
                              hipStream_t stream) {
    const float* x    = (const float*)d_in[0];
    const float* bias = (const float*)d_in[1];
    const float* upf  = (const float*)d_in[2];
    const float* dnf  = (const float*)d_in[3];
    float* out = (float*)d_out;

    const int n_blocks = 32 * 128 * 4;   // four quarter-slices per (n,c)
    const size_t lds_bytes = (size_t)LDS_WORDS * sizeof(float);
    hipLaunchKernelGGL(fused_upfirdn_lrelu, dim3(n_blocks), dim3(NT),
                       lds_bytes, stream, x, bias, upf, dnf, out);
}

// Round 15
// 75.353 us; speedup vs baseline: 1.5479x; 1.0571x over previous
//
#include <hip/hip_runtime.h>

// Fused upfirdn2d: up2(FIR12,H) -> up2(FIR12,W) -> +bias -> lrelu*sqrt2
//                  -> down2(FIR12,H) -> down2(FIR12,W)
// x: (32,128,64,64) f32.
// R15 = R9 VERBATIM (best: 73.2us) + exactly ONE change: P2/P3 lane groups
//   padded to 48 (multiple of 8) so 8-lane b128 groups never straddle
//   (cg,il) boundaries. R9->R10 decomposition: padding was worth ~+2%
//   (conflicts -2.4e6); R10's OTHER change (single-wave P4) cost ~4.5%.
//   Keep R9's 256-thread 1-row P4 (tail phases are latency-bound: more
//   waves beat fewer LDS instrs there).
//
// Index math:
//   z[i][c]  = sum_{j == i (mod 2)} (2*fu[j]) * x[(i-j)/2][c]
//   y[i][w]  = sum_{j == w (mod 2)} (2*fu[j]) * z[i][(w-j)/2]; lrelu(y+b)*g
//   yw[i][p] = sum_{j} fd[j] * y[i][2p+11-j]          (down-W; commutes w/ down-H)
//   out[o][p]= sum_{j} fd[j] * yw[2o+11-j][p]         (down-H)

#define NT 512
#define GAIN 1.41421356237309504880f
#define C1 (0.6f * GAIN)
#define C2 (0.4f * GAIN)

#define ZROWS 42              // quarter: out rows [o0,o0+16) -> z/y rows [2o0,2o0+42)
#define ZSTRIDE 84            // 336B = 80B mod 128 -> full rotation, row-walk
#define ZPAD 8                // local col p <-> real z col p-8 ; pads zeroed
#define YSTRIDE 148           // 592B = 80B mod 128 -> full rotation, row-walk
#define YWSTRIDE 68           // 272B = 16B mod 128 -> full rotation, row-walk

#define ZB_OFF 0
#define YB_OFF (ZROWS * ZSTRIDE)              // 3528
#define YW_OFF 0                              // yw[42][68]=2856 aliases zb (dead after P2)
#define LDS_FLOATS (YB_OFF + ZROWS * YSTRIDE) // 9744 floats = 38976 B -> 4 blk/CU

// wave-uniform float -> SGPR
__device__ __forceinline__ float sload(float v) {
    return __uint_as_float(__builtin_amdgcn_readfirstlane(__float_as_uint(v)));
}

__global__ __launch_bounds__(NT, 8) void fused_upfirdn_lrelu(
    const float* __restrict__ x,
    const float* __restrict__ bias,
    const float* __restrict__ upf,
    const float* __restrict__ dnf,
    float* __restrict__ out)
{
    extern __shared__ float lds[];
    float* zb = lds + ZB_OFF;
    float* yb = lds + YB_OFF;
    float* yw = lds + YW_OFF;

    const int t = threadIdx.x;
    const int bid = blockIdx.x;
    const int s = bid >> 2;           // slice = n*128 + c
    const int o0 = (bid & 3) << 4;    // 0,16,32,48
    const int c = s & 127;

    // filters + bias in SGPRs (uniform); fu pre-scaled by UP=2
    float fu[12], fd[12];
#pragma unroll
    for (int j = 0; j < 12; ++j) {
        fu[j] = sload(2.0f * upf[j]);
        fd[j] = sload(dnf[j]);
    }
    const float bv = sload(bias[c]);

    const float* xg = x + (size_t)s * 4096;
    float* outg = out + (size_t)s * 4096;

    // ---- P1: up-H from GLOBAL x -> z local rows [0,42).  t<336: task=(m,c4),
    //      z rows 2m,2m+1 from x rows M-5..M (M=o0+m), interior unchecked.
    //      t>=336: zero z pad cols [0,8) and [72,84). ----
    if (t < 336) {
        const int m = t >> 4;                 // 0..20
        const int c4 = (t & 15) << 2;
        const int M = o0 + m;
        float4 xv[6];
        if (M >= 5 && M <= 63) {              // interior: no bounds checks
#pragma unroll
            for (int d = 0; d < 6; ++d)
                xv[d] = *reinterpret_cast<const float4*>(xg + (M - 5 + d) * 64 + c4);
        } else {
#pragma unroll
            for (int d = 0; d < 6; ++d) {
                const int r = M - 5 + d;
                xv[d] = (r >= 0 && r <= 63)
                      ? *reinterpret_cast<const float4*>(xg + r * 64 + c4)
                      : make_float4(0.f, 0.f, 0.f, 0.f);
            }
        }
        float a0[4] = {0,0,0,0}, a1[4] = {0,0,0,0};
#pragma unroll
        for (int d = 0; d < 6; ++d) {         // tt = 5-d
            const float w0 = fu[2 * (5 - d)], w1 = fu[2 * (5 - d) + 1];
            a0[0] += w0 * xv[d].x; a0[1] += w0 * xv[d].y; a0[2] += w0 * xv[d].z; a0[3] += w0 * xv[d].w;
            a1[0] += w1 * xv[d].x; a1[1] += w1 * xv[d].y; a1[2] += w1 * xv[d].z; a1[3] += w1 * xv[d].w;
        }
        float* zr = zb + (2 * m) * ZSTRIDE + ZPAD + c4;
        *reinterpret_cast<float4*>(zr)           = make_float4(a0[0], a0[1], a0[2], a0[3]);
        *reinterpret_cast<float4*>(zr + ZSTRIDE) = make_float4(a1[0], a1[1], a1[2], a1[3]);
    } else {
        // 5 float4 pad-writes per row x 42 rows = 210 tasks over 176 threads
        for (int pt = t - 336; pt < 210; pt += 176) {
            const int rl = pt / 5;
            const int p = pt - rl * 5;
            const int col = (p < 2) ? (p << 2) : (72 + ((p - 2) << 2));
            *reinterpret_cast<float4*>(zb + rl * ZSTRIDE + col) = make_float4(0.f, 0.f, 0.f, 0.f);
        }
    }
    __syncthreads();

    // ---- P2: up-W + bias + lrelu -> y[42][148].  Groups of 48 (mult of 8),
    //      il fast-varying: 8-lane b128 groups have uniform cg and 336B
    //      lane stride (80B mod 128) -> conflict-free. t<432. ----
    if (t < 432) {
        const int cg = t / 48;                // 0..8
        const int il = t - cg * 48;
        if (il < ZROWS) {
            const int mbase = cg << 3;
            const float* zr = zb + il * ZSTRIDE + mbase;   // local col = real col + 8
            float zv[16];
#pragma unroll
            for (int q = 0; q < 4; ++q) {
                const float4 v = *reinterpret_cast<const float4*>(zr + (q << 2));
                zv[4 * q] = v.x; zv[4 * q + 1] = v.y; zv[4 * q + 2] = v.z; zv[4 * q + 3] = v.w;
            }
            float yv[16];
#pragma unroll
            for (int e = 0; e < 8; ++e) {     // m = mbase+e -> w = 2m, 2m+1
                float a0 = bv, a1 = bv;
#pragma unroll
                for (int tt = 0; tt < 6; ++tt) {
                    const float zz = zv[8 + e - tt];
                    a0 += fu[2 * tt]     * zz;
                    a1 += fu[2 * tt + 1] * zz;
                }
                yv[2 * e]     = C1 * a0 + C2 * fabsf(a0);   // g*lrelu
                yv[2 * e + 1] = C1 * a1 + C2 * fabsf(a1);
            }
            float* yr = yb + il * YSTRIDE + (mbase << 1);
#pragma unroll
            for (int q = 0; q < 4; ++q)
                *reinterpret_cast<float4*>(yr + (q << 2)) =
                    make_float4(yv[4 * q], yv[4 * q + 1], yv[4 * q + 2], yv[4 * q + 3]);
        }
    }
    __syncthreads();

    // ---- P3: down-W on y -> yw[42][64] (aliases zb).  Groups of 48,
    //      il fast-varying (592B lane stride = 80B mod 128 -> clean). t<384. ----
    if (t < 384) {
        const int cg = t / 48;                // 0..7 ; outputs p = 8cg..8cg+7
        const int il = t - cg * 48;
        if (il < ZROWS) {
            const float* yr = yb + il * YSTRIDE + (cg << 4);   // y cols 16cg..16cg+27
            float w[28];
#pragma unroll
            for (int q = 0; q < 7; ++q) {
                const float4 v = *reinterpret_cast<const float4*>(yr + (q << 2));
                w[4 * q] = v.x; w[4 * q + 1] = v.y; w[4 * q + 2] = v.z; w[4 * q + 3] = v.w;
            }
            float rv[8];
#pragma unroll
            for (int e = 0; e < 8; ++e) {     // p = 8cg+e : y cols 2p..2p+11
                float a = 0.0f;
#pragma unroll
                for (int j = 0; j < 12; ++j) a += fd[j] * w[2 * e + 11 - j];
                rv[e] = a;
            }
            float* wr = yw + il * YWSTRIDE + (cg << 3);
            *reinterpret_cast<float4*>(wr)     = make_float4(rv[0], rv[1], rv[2], rv[3]);
            *reinterpret_cast<float4*>(wr + 4) = make_float4(rv[4], rv[5], rv[6], rv[7]);
        }
    }
    __syncthreads();

    // ---- P4: down-H on yw -> GLOBAL out.  t<256 (R9 version: 4 waves,
    //      1 out row x 4 cols per task, 12 reads; latency-bound tail wants
    //      parallelism, not fewer instrs). ----
    if (t < 256) {
        const int o = t >> 4;                 // 0..15 ; out row o0+o
        const int col4 = (t & 15) << 2;       // 0..60
        const float* wr = yw + (2 * o) * YWSTRIDE + col4;   // yw rows 2o..2o+11
        float a0 = 0.f, a1 = 0.f, a2 = 0.f, a3 = 0.f;
#pragma unroll
        for (int rr = 0; rr < 12; ++rr) {     // j = 11-rr
            const float4 v = *reinterpret_cast<const float4*>(wr + rr * YWSTRIDE);
            const float ww = fd[11 - rr];
            a0 += ww * v.x; a1 += ww * v.y; a2 += ww * v.z; a3 += ww * v.w;
        }
        *reinterpret_cast<float4*>(outg + (o0 + o) * 64 + col4) =
            make_float4(a0, a1, a2, a3);
    }
}

extern "C" void kernel_launch(void* const* d_in, const int* in_sizes, int n_in,
                              void* d_out, int out_size, void* d_ws, size_t ws_size,
                              hipStream_t stream) {
    const float* x    = (const float*)d_in[0];
    const float* bias = (const float*)d_in[1];
    const float* upf  = (const float*)d_in[2];
    const float* dnf  = (const float*)d_in[3];
    float* out = (float*)d_out;

    const int n_blocks = 32 * 128 * 4;   // four quarter-slices per (n,c)
    const size_t lds_bytes = (size_t)LDS_FLOATS * sizeof(float);
    hipLaunchKernelGGL(fused_upfirdn_lrelu, dim3(n_blocks), dim3(NT),
                       lds_bytes, stream, x, bias, upf, dnf, out);
}

// Round 16
// 73.335 us; speedup vs baseline: 1.5905x; 1.0275x over previous
//
#include <hip/hip_runtime.h>

// Fused upfirdn2d: up2(FIR12,H) -> up2(FIR12,W) -> +bias -> lrelu*sqrt2
//                  -> down2(FIR12,H) -> down2(FIR12,W)
// x: (32,128,64,64) f32.
// R16 = R9 skeleton (best, 73.2us) with ALL LDS intermediates packed bf16.
//   Diagnosis: with measured b128 throughput (~12cy, 85B/cy — m134), R9's
//   ~181KB LDS traffic/block saturates the LDS pipe (~2850cy/block x 64
//   blocks/CU ~= full runtime). Conflict/occupancy knobs were +-5% because
//   the pipe itself was the roof. Fix: halve the BYTES.
//   z,y,yw stored as u32 bf16-pairs (v_cvt_pk_bf16_f32; shift/and unpack):
//   P1 wr 2xb128->2xb64; P2 rd 4->2 b128, wr 4->2; P3 rd 7->4, wr 2->1;
//   P4 rd 12xb128->12xb64.  ~90KB/block.  LDS 26.2KB, no aliasing.
//   Accuracy: bf16-y alone measured absmax 0.031 (R14) vs threshold 0.1056;
//   z+yw add ~0.01-0.02 more. Revert to R9 if validation fails.
//
// Index math:
//   z[i][c]  = sum_{j == i (mod 2)} (2*fu[j]) * x[(i-j)/2][c]
//   y[i][w]  = sum_{j == w (mod 2)} (2*fu[j]) * z[i][(w-j)/2]; lrelu(y+b)*g
//   yw[i][p] = sum_{j} fd[j] * y[i][2p+11-j]          (down-W; commutes w/ down-H)
//   out[o][p]= sum_{j} fd[j] * yw[2o+11-j][p]         (down-H)

#define NT 512
#define GAIN 1.41421356237309504880f
#define C1 (0.6f * GAIN)
#define C2 (0.4f * GAIN)

#define ZROWS 42
// u32 strides chosen for clean 8-lane row-walk rotation (stride*4 mod 128):
#define ZS 44    // 176B = 48B mod 128 -> 8 distinct 16B slots
#define YS 76    // 304B = 48B mod 128 -> clean
#define WS 36    // 144B = 16B mod 128 -> clean
// z u32 k <-> real z cols (2k-8, 2k-7): data k=4..35, pads k=0..3, 36..39
// y u32 k <-> y cols (2k, 2k+1): k=0..68 used
// yw u32 k <-> yw cols (2k, 2k+1): k=0..31 used

#define ZB_OFF 0
#define YB_OFF (ZROWS * ZS)              // 1848
#define YW_OFF (YB_OFF + ZROWS * YS)     // 1848+3192 = 5040
#define LDS_WORDS (YW_OFF + ZROWS * WS)  // 5040+1512 = 6552 u32 = 26208 B

// wave-uniform float -> SGPR
__device__ __forceinline__ float sload(float v) {
    return __uint_as_float(__builtin_amdgcn_readfirstlane(__float_as_uint(v)));
}
// pack two f32 -> u32 of 2xbf16; lo = a, hi = b
__device__ __forceinline__ unsigned int pk_bf16(float a, float b) {
    unsigned int r;
    asm("v_cvt_pk_bf16_f32 %0, %1, %2" : "=v"(r) : "v"(a), "v"(b));
    return r;
}
__device__ __forceinline__ float bl(unsigned int u) {  // lo bf16 -> f32
    return __uint_as_float(u << 16);
}
__device__ __forceinline__ float bh(unsigned int u) {  // hi bf16 -> f32
    return __uint_as_float(u & 0xffff0000u);
}

__global__ __launch_bounds__(NT, 8) void fused_upfirdn_lrelu(
    const float* __restrict__ x,
    const float* __restrict__ bias,
    const float* __restrict__ upf,
    const float* __restrict__ dnf,
    float* __restrict__ out)
{
    extern __shared__ unsigned int lds[];
    unsigned int* zb = lds + ZB_OFF;
    unsigned int* yb = lds + YB_OFF;
    unsigned int* yw = lds + YW_OFF;

    const int t = threadIdx.x;
    const int bid = blockIdx.x;
    const int s = bid >> 2;           // slice = n*128 + c
    const int o0 = (bid & 3) << 4;    // 0,16,32,48
    const int c = s & 127;

    float fu[12], fd[12];
#pragma unroll
    for (int j = 0; j < 12; ++j) {
        fu[j] = sload(2.0f * upf[j]);
        fd[j] = sload(dnf[j]);
    }
    const float bv = sload(bias[c]);

    const float* xg = x + (size_t)s * 4096;
    float* outg = out + (size_t)s * 4096;

    // ---- P1: up-H from GLOBAL x -> z (bf16) rows [0,42).  t<336: task=(m,c4),
    //      z rows 2m,2m+1 cols c4..c4+3 -> 2x b64.  t>=336: zero pads
    //      (k=0..3 and k=36..39, 2 uint4 per row x 42 = 84 tasks). ----
    if (t < 336) {
        const int m = t >> 4;                 // 0..20
        const int c4 = (t & 15) << 2;
        const int M = o0 + m;
        float4 xv[6];
        if (M >= 5 && M <= 63) {
#pragma unroll
            for (int d = 0; d < 6; ++d)
                xv[d] = *reinterpret_cast<const float4*>(xg + (M - 5 + d) * 64 + c4);
        } else {
#pragma unroll
            for (int d = 0; d < 6; ++d) {
                const int r = M - 5 + d;
                xv[d] = (r >= 0 && r <= 63)
                      ? *reinterpret_cast<const float4*>(xg + r * 64 + c4)
                      : make_float4(0.f, 0.f, 0.f, 0.f);
            }
        }
        float a0[4] = {0,0,0,0}, a1[4] = {0,0,0,0};
#pragma unroll
        for (int d = 0; d < 6; ++d) {         // tt = 5-d
            const float w0 = fu[2 * (5 - d)], w1 = fu[2 * (5 - d) + 1];
            a0[0] += w0 * xv[d].x; a0[1] += w0 * xv[d].y; a0[2] += w0 * xv[d].z; a0[3] += w0 * xv[d].w;
            a1[0] += w1 * xv[d].x; a1[1] += w1 * xv[d].y; a1[2] += w1 * xv[d].z; a1[3] += w1 * xv[d].w;
        }
        unsigned int* zr = zb + (2 * m) * ZS + (c4 >> 1) + 4;  // k = c4/2 + 4
        *reinterpret_cast<uint2*>(zr)      = make_uint2(pk_bf16(a0[0], a0[1]), pk_bf16(a0[2], a0[3]));
        *reinterpret_cast<uint2*>(zr + ZS) = make_uint2(pk_bf16(a1[0], a1[1]), pk_bf16(a1[2], a1[3]));
    } else {
        const int pt = t - 336;               // 84 pad tasks over 176 lanes
        if (pt < 84) {
            const int rl = pt >> 1;
            const int k = (pt & 1) ? 36 : 0;
            *reinterpret_cast<uint4*>(zb + rl * ZS + k) = make_uint4(0, 0, 0, 0);
        }
    }
    __syncthreads();

    // ---- P2: up-W + bias + lrelu -> y (bf16).  t<432: groups of 48,
    //      il fast-varying.  2x b128 rd (k=4cg..4cg+7 <-> real cols
    //      mbase-8..mbase+7), unpack 13 (j=3..15), 96 FMA, 8 cvt_pk,
    //      2x b128 wr at y k=8cg. ----
    if (t < 432) {
        const int cg = t / 48;                // 0..8 ; mbase = 8cg
        const int il = t - cg * 48;
        if (il < ZROWS) {
            const unsigned int* zr = zb + il * ZS + (cg << 2);
            const uint4 ua = *reinterpret_cast<const uint4*>(zr);
            const uint4 ub = *reinterpret_cast<const uint4*>(zr + 4);
            unsigned int u[8] = {ua.x, ua.y, ua.z, ua.w, ub.x, ub.y, ub.z, ub.w};
            float zf[16];                     // zf[j] <-> real col mbase-8+j; j=2..15 unpacked
#pragma unroll
            for (int k = 1; k < 8; ++k) {
                zf[2 * k]     = bl(u[k]);
                zf[2 * k + 1] = bh(u[k]);
            }
            unsigned int pk[8];
#pragma unroll
            for (int e = 0; e < 8; ++e) {     // m = 8cg+e -> y cols 2m,2m+1
                float a0 = bv, a1 = bv;
#pragma unroll
                for (int tt = 0; tt < 6; ++tt) {
                    const float zz = zf[8 + e - tt];   // j in [3,15]
                    a0 += fu[2 * tt]     * zz;
                    a1 += fu[2 * tt + 1] * zz;
                }
                const float y0 = C1 * a0 + C2 * fabsf(a0);   // g*lrelu
                const float y1 = C1 * a1 + C2 * fabsf(a1);
                pk[e] = pk_bf16(y0, y1);
            }
            unsigned int* yr = yb + il * YS + (cg << 3);
            *reinterpret_cast<uint4*>(yr)     = make_uint4(pk[0], pk[1], pk[2], pk[3]);
            *reinterpret_cast<uint4*>(yr + 4) = make_uint4(pk[4], pk[5], pk[6], pk[7]);
        }
    }
    __syncthreads();

    // ---- P3: down-W on bf16 y -> yw (bf16).  t<384: groups of 48, il fast.
    //      4x b128 rd (y k=8cg..8cg+15, use 13), 96 FMA, 4 cvt_pk, 1x b128 wr. ----
    if (t < 384) {
        const int cg = t / 48;                // 0..7 ; outputs p = 8cg..8cg+7
        const int il = t - cg * 48;
        if (il < ZROWS) {
            const unsigned int* yr = yb + il * YS + (cg << 3);
            unsigned int u[16];
#pragma unroll
            for (int q = 0; q < 4; ++q) {
                const uint4 v = *reinterpret_cast<const uint4*>(yr + (q << 2));
                u[4 * q] = v.x; u[4 * q + 1] = v.y; u[4 * q + 2] = v.z; u[4 * q + 3] = v.w;
            }
            float w[26];                      // y cols 16cg .. 16cg+25
#pragma unroll
            for (int k = 0; k < 13; ++k) {
                w[2 * k]     = bl(u[k]);
                w[2 * k + 1] = bh(u[k]);
            }
            float rv[8];
#pragma unroll
            for (int e = 0; e < 8; ++e) {     // p = 8cg+e : y cols 2p..2p+11
                float a = 0.0f;
#pragma unroll
                for (int j = 0; j < 12; ++j) a += fd[j] * w[2 * e + 11 - j];
                rv[e] = a;
            }
            *reinterpret_cast<uint4*>(yw + il * WS + (cg << 2)) =
                make_uint4(pk_bf16(rv[0], rv[1]), pk_bf16(rv[2], rv[3]),
                           pk_bf16(rv[4], rv[5]), pk_bf16(rv[6], rv[7]));
        }
    }
    __syncthreads();

    // ---- P4: down-H on bf16 yw -> GLOBAL out (f32).  t<256: task=(o,col4),
    //      12x b64 rd (rows 2o..2o+11), unpack, accumulate, 1 f32x4 store. ----
    if (t < 256) {
        const int o = t >> 4;                 // 0..15 ; out row o0+o
        const int col4 = (t & 15) << 2;       // 0..60
        const unsigned int* wr = yw + (2 * o) * WS + (col4 >> 1);
        float a0 = 0.f, a1 = 0.f, a2 = 0.f, a3 = 0.f;
#pragma unroll
        for (int rr = 0; rr < 12; ++rr) {     // j = 11-rr
            const uint2 v = *reinterpret_cast<const uint2*>(wr + rr * WS);
            const float ww = fd[11 - rr];
            a0 += ww * bl(v.x); a1 += ww * bh(v.x);
            a2 += ww * bl(v.y); a3 += ww * bh(v.y);
        }
        *reinterpret_cast<float4*>(outg + (o0 + o) * 64 + col4) =
            make_float4(a0, a1, a2, a3);
    }
}

extern "C" void kernel_launch(void* const* d_in, const int* in_sizes, int n_in,
                              void* d_out, int out_size, void* d_ws, size_t ws_size,
                              hipStream_t stream) {
    const float* x    = (const float*)d_in[0];
    const float* bias = (const float*)d_in[1];
    const float* upf  = (const float*)d_in[2];
    const float* dnf  = (const float*)d_in[3];
    float* out = (float*)d_out;

    const int n_blocks = 32 * 128 * 4;   // four quarter-slices per (n,c)
    const size_t lds_bytes = (size_t)LDS_WORDS * sizeof(unsigned int);
    hipLaunchKernelGGL(fused_upfirdn_lrelu, dim3(n_blocks), dim3(NT),
                       lds_bytes, stream, x, bias, upf, dnf, out);
}